// Round 12
// baseline (255.049 us; speedup 1.0000x reference)
//
#include <hip/hip_runtime.h>

#define ALPHA 5.0e-4f

typedef short s16x8 __attribute__((ext_vector_type(8)));
typedef unsigned short u16x8 __attribute__((ext_vector_type(8)));
typedef float f32x4 __attribute__((ext_vector_type(4)));

__device__ __forceinline__ unsigned short f2bf(float f) {
    unsigned int u = __builtin_bit_cast(unsigned int, f);
    u += 0x7fffu + ((u >> 16) & 1u);
    return (unsigned short)(u >> 16);
}
__device__ __forceinline__ float bf2f(unsigned short h) {
    return __builtin_bit_cast(float, (unsigned int)h << 16);
}
__device__ __forceinline__ f32x4 mfma16(s16x8 a, s16x8 b, f32x4 c) {
    return __builtin_amdgcn_mfma_f32_16x16x32_bf16(a, b, c, 0, 0, 0);
}

// ---------------------------------------------------------------------------
// Staging helpers -> LDS tile [ROWS][64 bf16], XOR-swizzled (slot ^= row&7).
// ---------------------------------------------------------------------------
template<int ROWS>
__device__ __forceinline__ void stage_kcontig(const float* __restrict__ src, int ld,
                                              unsigned short* __restrict__ lds, int tid)
{
#pragma unroll
    for (int it = 0; it < ROWS * 8 / 256; ++it) {
        const int g = tid + it * 256;
        const int row = g >> 3, s = g & 7;
        const float* p = src + (long long)row * ld + s * 8;
        const float4 x0 = *(const float4*)p;
        const float4 x1 = *(const float4*)(p + 4);
        u16x8 h;
        h[0] = f2bf(x0.x); h[1] = f2bf(x0.y); h[2] = f2bf(x0.z); h[3] = f2bf(x0.w);
        h[4] = f2bf(x1.x); h[5] = f2bf(x1.y); h[6] = f2bf(x1.z); h[7] = f2bf(x1.w);
        *(u16x8*)(lds + row * 64 + ((s ^ (row & 7)) << 3)) = h;
    }
}

template<int ROWS>
__device__ __forceinline__ void stage_kstrided(const float* __restrict__ src, int ld,
                                               unsigned short* __restrict__ lds, int tid)
{
    constexpr int KPT = ROWS * 64 / 256;
    const int m = tid % ROWS, kb = (tid / ROWS) * KPT;
#pragma unroll
    for (int j8 = 0; j8 < KPT / 8; ++j8) {
        u16x8 h;
#pragma unroll
        for (int j = 0; j < 8; ++j)
            h[j] = f2bf(src[(long long)(kb + j8 * 8 + j) * ld + m]);
        const int s = (kb >> 3) + j8;
        *(u16x8*)(lds + m * 64 + ((s ^ (m & 7)) << 3)) = h;
    }
}

template<int ROWS>
__device__ __forceinline__ void stage_kcontig_b(const unsigned short* __restrict__ src, int ld,
                                                unsigned short* __restrict__ lds, int tid)
{
#pragma unroll
    for (int it = 0; it < ROWS * 8 / 256; ++it) {
        const int g = tid + it * 256;
        const int row = g >> 3, s = g & 7;
        const u16x8 h = *(const u16x8*)(src + (long long)row * ld + s * 8);
        *(u16x8*)(lds + row * 64 + ((s ^ (row & 7)) << 3)) = h;
    }
}

template<int ROWS>
__device__ __forceinline__ void stage_kstrided_b(const unsigned short* __restrict__ src, int ld,
                                                 unsigned short* __restrict__ lds, int tid)
{
    constexpr int KPT = ROWS * 64 / 256;
    const int m = tid % ROWS, kb = (tid / ROWS) * KPT;
#pragma unroll
    for (int j8 = 0; j8 < KPT / 8; ++j8) {
        u16x8 h;
#pragma unroll
        for (int j = 0; j < 8; ++j)
            h[j] = src[(long long)(kb + j8 * 8 + j) * ld + m];
        const int s = (kb >> 3) + j8;
        *(u16x8*)(lds + m * 64 + ((s ^ (m & 7)) << 3)) = h;
    }
}

// ---------------------------------------------------------------------------
// GEMM device body (f32 inputs, f32 store):  D = op(A)@op(B)
// ---------------------------------------------------------------------------
template<int BM, int BN, bool TA, bool TB>
__device__ __forceinline__
void gemm_dev_f32(int bx, int by,
                  const float* __restrict__ A, int lda,
                  const float* __restrict__ B, int ldb,
                  float* __restrict__ D, int ldd, int Kd)
{
    constexpr int TWM = BM / 2, TWN = BN / 2;
    constexpr int FM = TWM / 16, FN = TWN / 16;
    __shared__ unsigned short As[BM * 64];
    __shared__ unsigned short Bs[BN * 64];

    const int tid = threadIdx.x;
    const int lane = tid & 63, w = tid >> 6;
    const int wm = w >> 1, wn = w & 1;
    const int lrow = lane & 15, lk = lane >> 4;
    const int m0 = by * BM, n0 = bx * BN;

    f32x4 acc[FM][FN];
#pragma unroll
    for (int i = 0; i < FM; ++i)
#pragma unroll
        for (int j = 0; j < FN; ++j) acc[i][j] = (f32x4){0.f, 0.f, 0.f, 0.f};

    for (int k0 = 0; k0 < Kd; k0 += 64) {
        if (!TA) stage_kcontig<BM>(A + (long long)m0 * lda + k0, lda, As, tid);
        else     stage_kstrided<BM>(A + (long long)k0 * lda + m0, lda, As, tid);
        if (TB)  stage_kcontig<BN>(B + (long long)n0 * ldb + k0, ldb, Bs, tid);
        else     stage_kstrided<BN>(B + (long long)k0 * ldb + n0, ldb, Bs, tid);
        __syncthreads();
#pragma unroll
        for (int kk = 0; kk < 2; ++kk) {
            s16x8 ah[FM], bh[FN];
#pragma unroll
            for (int i = 0; i < FM; ++i) {
                const int row = wm * TWM + i * 16 + lrow;
                const int s = kk * 4 + lk;
                ah[i] = *(const s16x8*)(As + row * 64 + ((s ^ (row & 7)) << 3));
            }
#pragma unroll
            for (int j = 0; j < FN; ++j) {
                const int col = wn * TWN + j * 16 + lrow;
                const int s = kk * 4 + lk;
                bh[j] = *(const s16x8*)(Bs + col * 64 + ((s ^ (col & 7)) << 3));
            }
#pragma unroll
            for (int i = 0; i < FM; ++i)
#pragma unroll
                for (int j = 0; j < FN; ++j)
                    acc[i][j] = mfma16(ah[i], bh[j], acc[i][j]);
        }
        __syncthreads();
    }

#pragma unroll
    for (int i = 0; i < FM; ++i)
#pragma unroll
        for (int j = 0; j < FN; ++j) {
            const int col = n0 + wn * TWN + j * 16 + lrow;
#pragma unroll
            for (int r = 0; r < 4; ++r) {
                const int row = m0 + wm * TWM + i * 16 + lk * 4 + r;
                D[(long long)row * ldd + col] = acc[i][j][r];
            }
        }
}

// ---------------------------------------------------------------------------
// fused_prep: blk%9==8 -> G1 partial GEMM (Gp[ky] = mm_ky @ mm_ky^T, plain
// stores, XCD-pinned: (9g+8)%8 == g%8 == ky); else zt/q prep.
// ---------------------------------------------------------------------------
__global__ __launch_bounds__(256)
void fused_prep_kernel(const float* __restrict__ zs, const float* __restrict__ no,
                       const float* __restrict__ zq, const float* __restrict__ mm,
                       unsigned short* __restrict__ ztb, float* __restrict__ q,
                       float* __restrict__ Gp)
{
    const int blk = blockIdx.x, t = threadIdx.x;
    if (blk % 9 == 8) {
        const int g = blk / 9;              // 0..511
        const int ky = g & 7;               // K-chunk
        const int tile = g >> 3;            // 0..63
        gemm_dev_f32<64, 64, false, true>(
            tile & 7, tile >> 3,
            mm + ky * 256, 2048, mm + ky * 256, 2048,
            Gp + (long long)ky * 262144, 512, 256);
    } else {
        const int bs = blk - blk / 9;       // 0..4095 = b*256 + s
        const int b = bs >> 8, sI = bs & 255;
        const long long in = ((long long)sI * 16 + b) * 2048 + t * 8;
        const f32x4 z0 = __builtin_nontemporal_load((const f32x4*)(zs + in));
        const f32x4 z1 = __builtin_nontemporal_load((const f32x4*)(zs + in + 4));
        const f32x4 n0 = __builtin_nontemporal_load((const f32x4*)(no + in));
        const f32x4 n1 = __builtin_nontemporal_load((const f32x4*)(no + in + 4));
        float zf[8];
#pragma unroll
        for (int j = 0; j < 4; ++j) {
            zf[j]     = fmaf(0.01f, n0[j], z0[j]);
            zf[j + 4] = fmaf(0.01f, n1[j], z1[j]);
        }
        u16x8 o;
#pragma unroll
        for (int j = 0; j < 8; ++j) o[j] = f2bf(zf[j]);
        *(u16x8*)(ztb + ((long long)bs * 2048 + t * 8)) = o;
        const float4 q0 = *(const float4*)(zq + b * 2048 + t * 8);
        const float4 q1 = *(const float4*)(zq + b * 2048 + t * 8 + 4);
        float qa = zf[0] * q0.x + zf[1] * q0.y + zf[2] * q0.z + zf[3] * q0.w
                 + zf[4] * q1.x + zf[5] * q1.y + zf[6] * q1.z + zf[7] * q1.w;
        __shared__ float red[256];
        red[t] = qa; __syncthreads();
        for (int st = 128; st > 0; st >>= 1) { if (t < st) red[t] += red[t + st]; __syncthreads(); }
        if (t == 0) q[bs] = red[0];
    }
}

// ---------------------------------------------------------------------------
// p1_zero: blocks 0..255: P1 = 8a*mm^T - 28a^2*(mm^T @ sum_ky Gp[ky]) -> bf16.
// blocks 256..264: zero wmean + Zrkv-region + dkl_M (before their accumulators).
// ---------------------------------------------------------------------------
__global__ __launch_bounds__(256)
void p1_zero_kernel(const float* __restrict__ mm, const float* __restrict__ Gp,
                    unsigned short* __restrict__ P1b,
                    float* __restrict__ wmean, float* __restrict__ out)
{
    const int blk = blockIdx.x, tid = threadIdx.x;
    if (blk < 256) {
        constexpr int BM = 64, BN = 64, TWM = 32, TWN = 32, FM = 2, FN = 2;
        __shared__ unsigned short As[BM * 64];
        __shared__ unsigned short Bs[BN * 64];
        const int bx = blk & 7, by = blk >> 3;   // n-tile 0..7, m-tile 0..31
        const int lane = tid & 63, w = tid >> 6;
        const int wm = w >> 1, wn = w & 1;
        const int lrow = lane & 15, lk = lane >> 4;
        const int m0 = by * BM, n0 = bx * BN;

        f32x4 acc[FM][FN];
#pragma unroll
        for (int i = 0; i < FM; ++i)
#pragma unroll
            for (int j = 0; j < FN; ++j) acc[i][j] = (f32x4){0.f, 0.f, 0.f, 0.f};

        for (int k0 = 0; k0 < 512; k0 += 64) {
            // A = mm^T (kstrided f32)
            stage_kstrided<BM>(mm + (long long)k0 * 2048 + m0, 2048, As, tid);
            // B = G1sum[k][n], summed over 8 partials (kstrided)
            {
                const int m = tid & 63, kb = (tid >> 6) * 16;
#pragma unroll
                for (int j8 = 0; j8 < 2; ++j8) {
                    u16x8 h;
#pragma unroll
                    for (int j = 0; j < 8; ++j) {
                        const long long off = (long long)(k0 + kb + j8 * 8 + j) * 512 + n0 + m;
                        float s = 0.f;
#pragma unroll
                        for (int p = 0; p < 8; ++p) s += Gp[(long long)p * 262144 + off];
                        h[j] = f2bf(s);
                    }
                    const int sl = (kb >> 3) + j8;
                    *(u16x8*)(Bs + m * 64 + ((sl ^ (m & 7)) << 3)) = h;
                }
            }
            __syncthreads();
#pragma unroll
            for (int kk = 0; kk < 2; ++kk) {
                s16x8 ah[FM], bh[FN];
#pragma unroll
                for (int i = 0; i < FM; ++i) {
                    const int row = wm * TWM + i * 16 + lrow;
                    const int s = kk * 4 + lk;
                    ah[i] = *(const s16x8*)(As + row * 64 + ((s ^ (row & 7)) << 3));
                }
#pragma unroll
                for (int j = 0; j < FN; ++j) {
                    const int col = wn * TWN + j * 16 + lrow;
                    const int s = kk * 4 + lk;
                    bh[j] = *(const s16x8*)(Bs + col * 64 + ((s ^ (col & 7)) << 3));
                }
#pragma unroll
                for (int i = 0; i < FM; ++i)
#pragma unroll
                    for (int j = 0; j < FN; ++j)
                        acc[i][j] = mfma16(ah[i], bh[j], acc[i][j]);
            }
            __syncthreads();
        }

        const float al = -28.0f * ALPHA * ALPHA, be = 8.0f * ALPHA;
#pragma unroll
        for (int i = 0; i < FM; ++i)
#pragma unroll
            for (int j = 0; j < FN; ++j) {
                const int col = n0 + wn * TWN + j * 16 + lrow;
#pragma unroll
                for (int r = 0; r < 4; ++r) {
                    const int row = m0 + wm * TWM + i * 16 + lk * 4 + r;
                    const float v = fmaf(be, mm[(long long)col * 2048 + row], al * acc[i][j][r]);
                    P1b[(long long)row * 512 + col] = f2bf(v);
                }
            }
    } else {
        const int zb = blk - 256;            // 0..8
        // zero Zrkv region: 73728 float4s over 9 blocks * 256 threads = 32 each
        float4* oz = (float4*)(out + 32768);
        const int base = (zb * 256 + tid) * 32;
#pragma unroll
        for (int i = 0; i < 32; ++i) oz[base + i] = (float4){0.f, 0.f, 0.f, 0.f};
        if (zb == 0) {
            float4* wm4 = (float4*)wmean;
            for (int i = tid; i < 2048; i += 256) wm4[i] = (float4){0.f, 0.f, 0.f, 0.f};
            if (tid == 0) out[327680] = 0.f;
        }
    }
}

// ---------------------------------------------------------------------------
// wT GEMM (zt @ P1 -> bf16 transposed) + fused u: wmean += 64a^2 * w^T q.
// 64x64 tiles, 512 blocks (2/CU), XCD-pinned A-panel reuse (same-by -> same XCD).
// ---------------------------------------------------------------------------
__global__ __launch_bounds__(256)
void wT_u_kernel(const unsigned short* __restrict__ ztb,
                 const unsigned short* __restrict__ P1b,
                 unsigned short* __restrict__ wTb,
                 const float* __restrict__ q, float* __restrict__ wmean)
{
    constexpr int BM = 64, BN = 64, TWM = 32, TWN = 32, FM = 2, FN = 2;
    __shared__ unsigned short As[BM * 64];
    __shared__ unsigned short Bs[BN * 64];
    const int lin = blockIdx.x;              // 512
    const int r = lin & 7, t = lin >> 3;     // t 0..63
    const int by = r + 8 * (t & 7), bx = t >> 3;  // by 0..63, bx 0..7
    const int tid = threadIdx.x;
    const int lane = tid & 63, w = tid >> 6;
    const int wm = w >> 1, wn = w & 1;
    const int lrow = lane & 15, lk = lane >> 4;
    const int m0 = by * BM, n0 = bx * BN;

    f32x4 acc[FM][FN];
#pragma unroll
    for (int i = 0; i < FM; ++i)
#pragma unroll
        for (int j = 0; j < FN; ++j) acc[i][j] = (f32x4){0.f, 0.f, 0.f, 0.f};

    for (int k0 = 0; k0 < 2048; k0 += 64) {
        stage_kcontig_b<BM>(ztb + (long long)m0 * 2048 + k0, 2048, As, tid);
        stage_kstrided_b<BN>(P1b + (long long)k0 * 512 + n0, 512, Bs, tid);
        __syncthreads();
#pragma unroll
        for (int kk = 0; kk < 2; ++kk) {
            s16x8 ah[FM], bh[FN];
#pragma unroll
            for (int i = 0; i < FM; ++i) {
                const int row = wm * TWM + i * 16 + lrow;
                const int s = kk * 4 + lk;
                ah[i] = *(const s16x8*)(As + row * 64 + ((s ^ (row & 7)) << 3));
            }
#pragma unroll
            for (int j = 0; j < FN; ++j) {
                const int col = wn * TWN + j * 16 + lrow;
                const int s = kk * 4 + lk;
                bh[j] = *(const s16x8*)(Bs + col * 64 + ((s ^ (col & 7)) << 3));
            }
#pragma unroll
            for (int i = 0; i < FM; ++i)
#pragma unroll
                for (int j = 0; j < FN; ++j)
                    acc[i][j] = mfma16(ah[i], bh[j], acc[i][j]);
        }
        __syncthreads();
    }

    float up[FN] = {0.f, 0.f};
#pragma unroll
    for (int i = 0; i < FM; ++i)
#pragma unroll
        for (int rr = 0; rr < 4; ++rr) {
            const int row = m0 + wm * TWM + i * 16 + lk * 4 + rr;
            const float qv = q[row];
#pragma unroll
            for (int j = 0; j < FN; ++j) {
                const int col = n0 + wn * TWN + j * 16 + lrow;
                const float v = acc[i][j][rr];
                wTb[(long long)(row >> 8) * 131072 + (long long)col * 256 + (row & 255)] = f2bf(v);
                up[j] = fmaf(v, qv, up[j]);
            }
        }
    const int b = m0 >> 8;
#pragma unroll
    for (int j = 0; j < FN; ++j) {
        float v = up[j];
        v += __shfl_xor(v, 16);
        v += __shfl_xor(v, 32);
        if (lk == 0) {
            const int col = n0 + wn * TWN + j * 16 + lrow;
            atomicAdd(&wmean[b * 512 + col], (64.0f * ALPHA * ALPHA) * v);
        }
    }
}

// ---------------------------------------------------------------------------
// tail1: blocks 0..255 zret (XCD-pinned by b); block 256 dkl_w.
// ---------------------------------------------------------------------------
__global__ __launch_bounds__(256)
void tail1_kernel(const unsigned short* __restrict__ wTb,
                  const unsigned short* __restrict__ ztb,
                  const float* __restrict__ wmean, const float* __restrict__ wlv,
                  float* __restrict__ out)
{
    __shared__ __align__(16) float smemf[1024];
    const int blk = blockIdx.x, tid = threadIdx.x;
    if (blk < 256) {
        float* wms = smemf;                  // 512
        float* ys  = smemf + 512;            // 256
        float* red2 = smemf + 768;           // 256
        const int r8 = blk & 7, t8 = blk >> 3;
        const int b = r8 + 8 * (t8 & 1), ct = t8 >> 1;   // b XCD-pinned
        wms[tid] = wmean[b * 512 + tid];
        wms[tid + 256] = wmean[b * 512 + 256 + tid];
        __syncthreads();
        {
            const unsigned short* wp = wTb + (long long)b * 131072 + tid;
            float yv = 0.f;
#pragma unroll 8
            for (int k = 0; k < 512; ++k)
                yv = fmaf(wms[k], bf2f(wp[(long long)k * 256]), yv);
            ys[tid] = yv;
        }
        __syncthreads();
        const int c = ct * 128 + (tid & 127), sh = tid >> 7;
        const unsigned short* zp = ztb + (long long)b * 524288 + c;
        float acc2 = 0.f;
        const int sbase = sh * 128;
#pragma unroll 8
        for (int s = 0; s < 128; ++s)
            acc2 = fmaf(ys[sbase + s], bf2f(zp[(long long)(sbase + s) * 2048]), acc2);
        red2[tid] = acc2; __syncthreads();
        if (sh == 0)
            out[(long long)b * 2048 + c] = (8.0f * ALPHA) * (red2[tid] + red2[tid + 128]);
    } else {
        float* red = smemf;
        float s = 0.f;
        for (int i = tid; i < 16 * 512; i += 256) { const float v = wmean[i]; s += v * v; }
        red[tid] = s; __syncthreads();
        for (int st = 128; st > 0; st >>= 1) { if (tid < st) red[tid] += red[tid + st]; __syncthreads(); }
        if (tid == 0) {
            const float l = wlv[0];
            out[327681] = 0.5f * (red[0] + 8192.0f * (expf(l) - 1.0f - l));
        }
    }
}

// ---------------------------------------------------------------------------
// tail2: interleaved co-launch of nmm+dkl (1024 blocks, compute) and zrkv
// (2304 blocks, HBM NT stream, atomicAdd into pre-zeroed out). 26 = 8 + 18.
// ---------------------------------------------------------------------------
__global__ __launch_bounds__(256)
void tail2_kernel(const unsigned short* __restrict__ wTb,
                  const unsigned short* __restrict__ ztb,
                  const float* __restrict__ mm, const float* __restrict__ mlv,
                  const float* __restrict__ WM, float* __restrict__ out)
{
    __shared__ __align__(16) unsigned char smem[34304];
    const int g = blockIdx.x, tid = threadIdx.x;
    const int grp = g / 26, p = g % 26;
    if (p < 8) {
        constexpr int BM = 128, BN = 128, TWM = 64, TWN = 64, FM = 4, FN = 4;
        unsigned short* As = (unsigned short*)smem;
        unsigned short* Bs = As + BM * 64;
        float* ivars = (float*)(smem + 32768);
        float* red = (float*)(smem + 33280);
        const int bz = ((2 * grp + p) & 7) + 8 * (grp & 1);
        const int rest = grp >> 1;
        const int by = rest & 3, bx = rest >> 2;
        const int lane = tid & 63, w = tid >> 6;
        const int wm = w >> 1, wn = w & 1;
        const int lrow = lane & 15, lk = lane >> 4;
        const int m0 = by * BM, n0 = bx * BN;

        if (tid < 128) ivars[tid] = 1.0f / (expf(mlv[m0 + tid]) + 1e-6f);

        f32x4 acc[FM][FN];
#pragma unroll
        for (int i = 0; i < FM; ++i)
#pragma unroll
            for (int j = 0; j < FN; ++j) acc[i][j] = (f32x4){0.f, 0.f, 0.f, 0.f};

        for (int k0 = 0; k0 < 256; k0 += 64) {
            stage_kcontig_b<BM>(wTb + (long long)bz * 131072 + (long long)m0 * 256 + k0, 256, As, tid);
            stage_kstrided_b<BN>(ztb + (long long)bz * 524288 + (long long)k0 * 2048 + n0, 2048, Bs, tid);
            __syncthreads();
#pragma unroll
            for (int kk = 0; kk < 2; ++kk) {
                s16x8 ah[FM], bh[FN];
#pragma unroll
                for (int i = 0; i < FM; ++i) {
                    const int row = wm * TWM + i * 16 + lrow;
                    const int s = kk * 4 + lk;
                    ah[i] = *(const s16x8*)(As + row * 64 + ((s ^ (row & 7)) << 3));
                }
#pragma unroll
                for (int j = 0; j < FN; ++j) {
                    const int col = wn * TWN + j * 16 + lrow;
                    const int s = kk * 4 + lk;
                    bh[j] = *(const s16x8*)(Bs + col * 64 + ((s ^ (col & 7)) << 3));
                }
#pragma unroll
                for (int i = 0; i < FM; ++i)
#pragma unroll
                    for (int j = 0; j < FN; ++j)
                        acc[i][j] = mfma16(ah[i], bh[j], acc[i][j]);
            }
            __syncthreads();
        }

        const float A8 = 8.0f * ALPHA;
        float da = 0.f;
#pragma unroll
        for (int i = 0; i < FM; ++i)
#pragma unroll
            for (int j = 0; j < FN; ++j) {
                const int cl = wn * TWN + j * 16 + lrow;
#pragma unroll
                for (int rr = 0; rr < 4; ++rr) {
                    const int rl = wm * TWM + i * 16 + lk * 4 + rr;
                    const float v = A8 * acc[i][j][rr];
                    const float d = v - mm[(long long)(m0 + rl) * 2048 + (n0 + cl)];
                    da = fmaf(d * d, ivars[rl], da);
                }
            }
        red[tid] = da; __syncthreads();
        for (int st = 128; st > 0; st >>= 1) { if (tid < st) red[tid] += red[tid + st]; __syncthreads(); }
        if (tid == 0) atomicAdd(&out[327680], red[0] * (1.0f / 16.0f));
    } else {
        const int z = grp * 18 + (p - 8);        // 0..2303
        const int bx = z % 288, ky = z / 288;
        const int lane = tid & 63, w = tid >> 6;
        const int d0 = bx * 64 + w * 16;
        const int kc0 = ky * 256;
        const int rr = lane & 15, kq = lane >> 4;
        const float* zr = out;                   // out[0..32768) = z_retrieved
        s16x8 areg[8];
        const float* zb = zr + rr * 2048 + kc0 + kq * 8;
#pragma unroll
        for (int s = 0; s < 8; ++s) {
            const f32x4 a0 = *(const f32x4*)(zb + s * 32);
            const f32x4 a1 = *(const f32x4*)(zb + s * 32 + 4);
            u16x8 h;
#pragma unroll
            for (int j = 0; j < 4; ++j) { h[j] = f2bf(a0[j]); h[j + 4] = f2bf(a1[j]); }
            areg[s] = __builtin_bit_cast(s16x8, h);
        }
        f32x4 acc = {0.f, 0.f, 0.f, 0.f};
        const float* wb = WM + (long long)(d0 + rr) * 2048 + kc0 + kq * 8;
#pragma unroll
        for (int s = 0; s < 8; ++s) {
            const f32x4 b0 = __builtin_nontemporal_load((const f32x4*)(wb + s * 32));
            const f32x4 b1 = __builtin_nontemporal_load((const f32x4*)(wb + s * 32 + 4));
            u16x8 h;
#pragma unroll
            for (int j = 0; j < 4; ++j) { h[j] = f2bf(b0[j]); h[j + 4] = f2bf(b1[j]); }
            acc = mfma16(areg[s], __builtin_bit_cast(s16x8, h), acc);
        }
        float* oz = out + 32768;
#pragma unroll
        for (int r = 0; r < 4; ++r)
            atomicAdd(&oz[(long long)(kq * 4 + r) * 18432 + d0 + rr], acc[r]);
    }
}

extern "C" void kernel_launch(void* const* d_in, const int* in_sizes, int n_in,
                              void* d_out, int out_size, void* d_ws, size_t ws_size,
                              hipStream_t stream)
{
    (void)in_sizes; (void)n_in; (void)out_size; (void)ws_size;
    const float* z_seq   = (const float*)d_in[0];
    const float* z_query = (const float*)d_in[1];
    const float* noise   = (const float*)d_in[2];
    const float* mm      = (const float*)d_in[3];
    const float* mlv     = (const float*)d_in[4];
    const float* wlv     = (const float*)d_in[5];
    const float* WM      = (const float*)d_in[6];
    float* out = (float*)d_out;   // [zr 32768 | Zrkv 294912 | dkl_M | dkl_w]

    char* wsb = (char*)d_ws;
    unsigned short* ztb  = (unsigned short*)(wsb);                  // 16 MB (B,S,C) bf16
    unsigned short* wTb  = (unsigned short*)(wsb + (16LL << 20));   // 4 MB (B,K,S) bf16
    float*          Gp   = (float*)(wsb + (24LL << 20));            // 8 MB: 8x (K,K) partials
    unsigned short* P1b  = (unsigned short*)(wsb + (32LL << 20));   // 2 MB (C,K) bf16
    float*          qvec = (float*)(wsb + (36LL << 20));            // 16 KB
    float*          wmean = (float*)(wsb + (37LL << 20));           // 32 KB

    // 1. prep (zt + q) || G1 K-split partials (interleaved every 9th block)
    fused_prep_kernel<<<4608, 256, 0, stream>>>(z_seq, noise, z_query, mm,
                                                ztb, qvec, Gp);
    // 2. P1 (sums Gp partials) || zero wmean/Zrkv/dkl_M
    p1_zero_kernel<<<265, 256, 0, stream>>>(mm, Gp, P1b, wmean, out);
    // 3. wT = (zt @ P1)^T bf16, + fused u -> wmean (atomics); 64x64, 2 blocks/CU
    wT_u_kernel<<<512, 256, 0, stream>>>(ztb, P1b, wTb, qvec, wmean);
    // 4. zret + dkl_w (needs wmean)
    tail1_kernel<<<257, 256, 0, stream>>>(wTb, ztb, wmean, wlv, out);
    // 5. co-launched nmm+dkl_M (compute) || zrkv stream (HBM), interleaved 8:18
    tail2_kernel<<<3328, 256, 0, stream>>>(wTb, ztb, mm, mlv, WM, out);
}

// Round 13
// 164.037 us; speedup vs baseline: 1.5548x; 1.5548x over previous
//
#include <hip/hip_runtime.h>

#define ALPHA 5.0e-4f

typedef short s16x8 __attribute__((ext_vector_type(8)));
typedef unsigned short u16x8 __attribute__((ext_vector_type(8)));
typedef unsigned short u16x4 __attribute__((ext_vector_type(4)));
typedef float f32x4 __attribute__((ext_vector_type(4)));

__device__ __forceinline__ unsigned short f2bf(float f) {
    unsigned int u = __builtin_bit_cast(unsigned int, f);
    u += 0x7fffu + ((u >> 16) & 1u);
    return (unsigned short)(u >> 16);
}
__device__ __forceinline__ float bf2f(unsigned short h) {
    return __builtin_bit_cast(float, (unsigned int)h << 16);
}
__device__ __forceinline__ f32x4 mfma16(s16x8 a, s16x8 b, f32x4 c) {
    return __builtin_amdgcn_mfma_f32_16x16x32_bf16(a, b, c, 0, 0, 0);
}

// ---------------------------------------------------------------------------
// Staging helpers -> LDS tile [ROWS][64 bf16], XOR-swizzled (slot ^= row&7).
// ---------------------------------------------------------------------------
template<int ROWS>
__device__ __forceinline__ void stage_kcontig(const float* __restrict__ src, int ld,
                                              unsigned short* __restrict__ lds, int tid)
{
#pragma unroll
    for (int it = 0; it < ROWS * 8 / 256; ++it) {
        const int g = tid + it * 256;
        const int row = g >> 3, s = g & 7;
        const float* p = src + (long long)row * ld + s * 8;
        const float4 x0 = *(const float4*)p;
        const float4 x1 = *(const float4*)(p + 4);
        u16x8 h;
        h[0] = f2bf(x0.x); h[1] = f2bf(x0.y); h[2] = f2bf(x0.z); h[3] = f2bf(x0.w);
        h[4] = f2bf(x1.x); h[5] = f2bf(x1.y); h[6] = f2bf(x1.z); h[7] = f2bf(x1.w);
        *(u16x8*)(lds + row * 64 + ((s ^ (row & 7)) << 3)) = h;
    }
}

template<int ROWS>
__device__ __forceinline__ void stage_kstrided(const float* __restrict__ src, int ld,
                                               unsigned short* __restrict__ lds, int tid)
{
    constexpr int KPT = ROWS * 64 / 256;
    const int m = tid % ROWS, kb = (tid / ROWS) * KPT;
#pragma unroll
    for (int j8 = 0; j8 < KPT / 8; ++j8) {
        u16x8 h;
#pragma unroll
        for (int j = 0; j < 8; ++j)
            h[j] = f2bf(src[(long long)(kb + j8 * 8 + j) * ld + m]);
        const int s = (kb >> 3) + j8;
        *(u16x8*)(lds + m * 64 + ((s ^ (m & 7)) << 3)) = h;
    }
}

template<int ROWS>
__device__ __forceinline__ void stage_kcontig_b(const unsigned short* __restrict__ src, int ld,
                                                unsigned short* __restrict__ lds, int tid)
{
#pragma unroll
    for (int it = 0; it < ROWS * 8 / 256; ++it) {
        const int g = tid + it * 256;
        const int row = g >> 3, s = g & 7;
        const u16x8 h = *(const u16x8*)(src + (long long)row * ld + s * 8);
        *(u16x8*)(lds + row * 64 + ((s ^ (row & 7)) << 3)) = h;
    }
}

template<int ROWS>
__device__ __forceinline__ void stage_kstrided_b(const unsigned short* __restrict__ src, int ld,
                                                 unsigned short* __restrict__ lds, int tid)
{
    constexpr int KPT = ROWS * 64 / 256;
    const int m = tid % ROWS, kb = (tid / ROWS) * KPT;
#pragma unroll
    for (int j8 = 0; j8 < KPT / 8; ++j8) {
        u16x8 h;
#pragma unroll
        for (int j = 0; j < 8; ++j)
            h[j] = src[(long long)(kb + j8 * 8 + j) * ld + m];
        const int s = (kb >> 3) + j8;
        *(u16x8*)(lds + m * 64 + ((s ^ (m & 7)) << 3)) = h;
    }
}

// ---------------------------------------------------------------------------
// GEMM device body (f32 inputs, f32 store):  D = op(A)@op(B)
// ---------------------------------------------------------------------------
template<int BM, int BN, bool TA, bool TB>
__device__ __forceinline__
void gemm_dev_f32(int bx, int by,
                  const float* __restrict__ A, int lda,
                  const float* __restrict__ B, int ldb,
                  float* __restrict__ D, int ldd, int Kd)
{
    constexpr int TWM = BM / 2, TWN = BN / 2;
    constexpr int FM = TWM / 16, FN = TWN / 16;
    __shared__ unsigned short As[BM * 64];
    __shared__ unsigned short Bs[BN * 64];

    const int tid = threadIdx.x;
    const int lane = tid & 63, w = tid >> 6;
    const int wm = w >> 1, wn = w & 1;
    const int lrow = lane & 15, lk = lane >> 4;
    const int m0 = by * BM, n0 = bx * BN;

    f32x4 acc[FM][FN];
#pragma unroll
    for (int i = 0; i < FM; ++i)
#pragma unroll
        for (int j = 0; j < FN; ++j) acc[i][j] = (f32x4){0.f, 0.f, 0.f, 0.f};

    for (int k0 = 0; k0 < Kd; k0 += 64) {
        if (!TA) stage_kcontig<BM>(A + (long long)m0 * lda + k0, lda, As, tid);
        else     stage_kstrided<BM>(A + (long long)k0 * lda + m0, lda, As, tid);
        if (TB)  stage_kcontig<BN>(B + (long long)n0 * ldb + k0, ldb, Bs, tid);
        else     stage_kstrided<BN>(B + (long long)k0 * ldb + n0, ldb, Bs, tid);
        __syncthreads();
#pragma unroll
        for (int kk = 0; kk < 2; ++kk) {
            s16x8 ah[FM], bh[FN];
#pragma unroll
            for (int i = 0; i < FM; ++i) {
                const int row = wm * TWM + i * 16 + lrow;
                const int s = kk * 4 + lk;
                ah[i] = *(const s16x8*)(As + row * 64 + ((s ^ (row & 7)) << 3));
            }
#pragma unroll
            for (int j = 0; j < FN; ++j) {
                const int col = wn * TWN + j * 16 + lrow;
                const int s = kk * 4 + lk;
                bh[j] = *(const s16x8*)(Bs + col * 64 + ((s ^ (col & 7)) << 3));
            }
#pragma unroll
            for (int i = 0; i < FM; ++i)
#pragma unroll
                for (int j = 0; j < FN; ++j)
                    acc[i][j] = mfma16(ah[i], bh[j], acc[i][j]);
        }
        __syncthreads();
    }

#pragma unroll
    for (int i = 0; i < FM; ++i)
#pragma unroll
        for (int j = 0; j < FN; ++j) {
            const int col = n0 + wn * TWN + j * 16 + lrow;
#pragma unroll
            for (int r = 0; r < 4; ++r) {
                const int row = m0 + wm * TWM + i * 16 + lk * 4 + r;
                D[(long long)row * ldd + col] = acc[i][j][r];
            }
        }
}

// ---------------------------------------------------------------------------
// fused_prep: blk%9==8 -> G1 partial GEMM (Gp[ky] = mm_ky @ mm_ky^T, plain
// stores); else zt/q prep.
// ---------------------------------------------------------------------------
__global__ __launch_bounds__(256)
void fused_prep_kernel(const float* __restrict__ zs, const float* __restrict__ no,
                       const float* __restrict__ zq, const float* __restrict__ mm,
                       unsigned short* __restrict__ ztb, float* __restrict__ q,
                       float* __restrict__ Gp)
{
    const int blk = blockIdx.x, t = threadIdx.x;
    if (blk % 9 == 8) {
        const int g = blk / 9;              // 0..511
        const int ky = g & 7;               // K-chunk
        const int tile = g >> 3;            // 0..63
        gemm_dev_f32<64, 64, false, true>(
            tile & 7, tile >> 3,
            mm + ky * 256, 2048, mm + ky * 256, 2048,
            Gp + (long long)ky * 262144, 512, 256);
    } else {
        const int bs = blk - blk / 9;       // 0..4095 = b*256 + s
        const int b = bs >> 8, sI = bs & 255;
        const long long in = ((long long)sI * 16 + b) * 2048 + t * 8;
        const f32x4 z0 = __builtin_nontemporal_load((const f32x4*)(zs + in));
        const f32x4 z1 = __builtin_nontemporal_load((const f32x4*)(zs + in + 4));
        const f32x4 n0 = __builtin_nontemporal_load((const f32x4*)(no + in));
        const f32x4 n1 = __builtin_nontemporal_load((const f32x4*)(no + in + 4));
        float zf[8];
#pragma unroll
        for (int j = 0; j < 4; ++j) {
            zf[j]     = fmaf(0.01f, n0[j], z0[j]);
            zf[j + 4] = fmaf(0.01f, n1[j], z1[j]);
        }
        u16x8 o;
#pragma unroll
        for (int j = 0; j < 8; ++j) o[j] = f2bf(zf[j]);
        *(u16x8*)(ztb + ((long long)bs * 2048 + t * 8)) = o;
        const float4 q0 = *(const float4*)(zq + b * 2048 + t * 8);
        const float4 q1 = *(const float4*)(zq + b * 2048 + t * 8 + 4);
        float qa = zf[0] * q0.x + zf[1] * q0.y + zf[2] * q0.z + zf[3] * q0.w
                 + zf[4] * q1.x + zf[5] * q1.y + zf[6] * q1.z + zf[7] * q1.w;
        __shared__ float red[256];
        red[t] = qa; __syncthreads();
        for (int st = 128; st > 0; st >>= 1) { if (t < st) red[t] += red[t + st]; __syncthreads(); }
        if (t == 0) q[bs] = red[0];
    }
}

// ---------------------------------------------------------------------------
// g1_reduce_zero: blocks 0..255: G1b = bf16(sum_ky Gp[ky]) (vectorized,
// coalesced). blocks 256..264: zero wmean + Zrkv-region + dkl_M.
// ---------------------------------------------------------------------------
__global__ __launch_bounds__(256)
void g1_reduce_zero_kernel(const float* __restrict__ Gp,
                           unsigned short* __restrict__ G1b,
                           float* __restrict__ wmean, float* __restrict__ out)
{
    const int blk = blockIdx.x, tid = threadIdx.x;
    if (blk < 256) {
        const int idx = blk * 256 + tid;     // 0..65535 float4s
        f32x4 s = {0.f, 0.f, 0.f, 0.f};
#pragma unroll
        for (int p = 0; p < 8; ++p) {
            const f32x4 v = *(const f32x4*)(Gp + (long long)p * 262144 + idx * 4);
            s[0] += v[0]; s[1] += v[1]; s[2] += v[2]; s[3] += v[3];
        }
        u16x4 h;
#pragma unroll
        for (int j = 0; j < 4; ++j) h[j] = f2bf(s[j]);
        *(u16x4*)(G1b + idx * 4) = h;
    } else {
        const int zb = blk - 256;            // 0..8
        float4* oz = (float4*)(out + 32768);
        const int base = (zb * 256 + tid) * 32;
#pragma unroll
        for (int i = 0; i < 32; ++i) oz[base + i] = (float4){0.f, 0.f, 0.f, 0.f};
        if (zb == 0) {
            float4* wm4 = (float4*)wmean;
            for (int i = tid; i < 2048; i += 256) wm4[i] = (float4){0.f, 0.f, 0.f, 0.f};
            if (tid == 0) out[327680] = 0.f;
        }
    }
}

// ---------------------------------------------------------------------------
// p1: P1 = 8a*mm^T - 28a^2*(mm^T @ G1) -> bf16  (2048,512,512), 64x64 tiles.
// ---------------------------------------------------------------------------
__global__ __launch_bounds__(256)
void p1_kernel(const float* __restrict__ mm, const unsigned short* __restrict__ G1b,
               unsigned short* __restrict__ P1b)
{
    constexpr int BM = 64, BN = 64, TWM = 32, TWN = 32, FM = 2, FN = 2;
    __shared__ unsigned short As[BM * 64];
    __shared__ unsigned short Bs[BN * 64];
    const int blk = blockIdx.x;
    const int bx = blk & 7, by = blk >> 3;   // n-tile 0..7, m-tile 0..31
    const int tid = threadIdx.x;
    const int lane = tid & 63, w = tid >> 6;
    const int wm = w >> 1, wn = w & 1;
    const int lrow = lane & 15, lk = lane >> 4;
    const int m0 = by * BM, n0 = bx * BN;

    f32x4 acc[FM][FN];
#pragma unroll
    for (int i = 0; i < FM; ++i)
#pragma unroll
        for (int j = 0; j < FN; ++j) acc[i][j] = (f32x4){0.f, 0.f, 0.f, 0.f};

    for (int k0 = 0; k0 < 512; k0 += 64) {
        stage_kstrided<BM>(mm + (long long)k0 * 2048 + m0, 2048, As, tid);
        stage_kstrided_b<BN>(G1b + (long long)k0 * 512 + n0, 512, Bs, tid);
        __syncthreads();
#pragma unroll
        for (int kk = 0; kk < 2; ++kk) {
            s16x8 ah[FM], bh[FN];
#pragma unroll
            for (int i = 0; i < FM; ++i) {
                const int row = wm * TWM + i * 16 + lrow;
                const int s = kk * 4 + lk;
                ah[i] = *(const s16x8*)(As + row * 64 + ((s ^ (row & 7)) << 3));
            }
#pragma unroll
            for (int j = 0; j < FN; ++j) {
                const int col = wn * TWN + j * 16 + lrow;
                const int s = kk * 4 + lk;
                bh[j] = *(const s16x8*)(Bs + col * 64 + ((s ^ (col & 7)) << 3));
            }
#pragma unroll
            for (int i = 0; i < FM; ++i)
#pragma unroll
                for (int j = 0; j < FN; ++j)
                    acc[i][j] = mfma16(ah[i], bh[j], acc[i][j]);
        }
        __syncthreads();
    }

    const float al = -28.0f * ALPHA * ALPHA, be = 8.0f * ALPHA;
#pragma unroll
    for (int i = 0; i < FM; ++i)
#pragma unroll
        for (int j = 0; j < FN; ++j) {
            const int col = n0 + wn * TWN + j * 16 + lrow;
#pragma unroll
            for (int r = 0; r < 4; ++r) {
                const int row = m0 + wm * TWM + i * 16 + lk * 4 + r;
                const float v = fmaf(be, mm[(long long)col * 2048 + row], al * acc[i][j][r]);
                P1b[(long long)row * 512 + col] = f2bf(v);
            }
        }
}

// ---------------------------------------------------------------------------
// wT GEMM (zt @ P1 -> bf16 transposed) + fused u: wmean += 64a^2 * w^T q.
// 64x64 tiles, 512 blocks (2/CU), XCD-pinned A-panel reuse.
// ---------------------------------------------------------------------------
__global__ __launch_bounds__(256)
void wT_u_kernel(const unsigned short* __restrict__ ztb,
                 const unsigned short* __restrict__ P1b,
                 unsigned short* __restrict__ wTb,
                 const float* __restrict__ q, float* __restrict__ wmean)
{
    constexpr int BM = 64, BN = 64, TWM = 32, TWN = 32, FM = 2, FN = 2;
    __shared__ unsigned short As[BM * 64];
    __shared__ unsigned short Bs[BN * 64];
    const int lin = blockIdx.x;              // 512
    const int r = lin & 7, t = lin >> 3;     // t 0..63
    const int by = r + 8 * (t & 7), bx = t >> 3;  // by 0..63, bx 0..7
    const int tid = threadIdx.x;
    const int lane = tid & 63, w = tid >> 6;
    const int wm = w >> 1, wn = w & 1;
    const int lrow = lane & 15, lk = lane >> 4;
    const int m0 = by * BM, n0 = bx * BN;

    f32x4 acc[FM][FN];
#pragma unroll
    for (int i = 0; i < FM; ++i)
#pragma unroll
        for (int j = 0; j < FN; ++j) acc[i][j] = (f32x4){0.f, 0.f, 0.f, 0.f};

    for (int k0 = 0; k0 < 2048; k0 += 64) {
        stage_kcontig_b<BM>(ztb + (long long)m0 * 2048 + k0, 2048, As, tid);
        stage_kstrided_b<BN>(P1b + (long long)k0 * 512 + n0, 512, Bs, tid);
        __syncthreads();
#pragma unroll
        for (int kk = 0; kk < 2; ++kk) {
            s16x8 ah[FM], bh[FN];
#pragma unroll
            for (int i = 0; i < FM; ++i) {
                const int row = wm * TWM + i * 16 + lrow;
                const int s = kk * 4 + lk;
                ah[i] = *(const s16x8*)(As + row * 64 + ((s ^ (row & 7)) << 3));
            }
#pragma unroll
            for (int j = 0; j < FN; ++j) {
                const int col = wn * TWN + j * 16 + lrow;
                const int s = kk * 4 + lk;
                bh[j] = *(const s16x8*)(Bs + col * 64 + ((s ^ (col & 7)) << 3));
            }
#pragma unroll
            for (int i = 0; i < FM; ++i)
#pragma unroll
                for (int j = 0; j < FN; ++j)
                    acc[i][j] = mfma16(ah[i], bh[j], acc[i][j]);
        }
        __syncthreads();
    }

    float up[FN] = {0.f, 0.f};
#pragma unroll
    for (int i = 0; i < FM; ++i)
#pragma unroll
        for (int rr = 0; rr < 4; ++rr) {
            const int row = m0 + wm * TWM + i * 16 + lk * 4 + rr;
            const float qv = q[row];
#pragma unroll
            for (int j = 0; j < FN; ++j) {
                const int col = n0 + wn * TWN + j * 16 + lrow;
                const float v = acc[i][j][rr];
                wTb[(long long)(row >> 8) * 131072 + (long long)col * 256 + (row & 255)] = f2bf(v);
                up[j] = fmaf(v, qv, up[j]);
            }
        }
    const int b = m0 >> 8;
#pragma unroll
    for (int j = 0; j < FN; ++j) {
        float v = up[j];
        v += __shfl_xor(v, 16);
        v += __shfl_xor(v, 32);
        if (lk == 0) {
            const int col = n0 + wn * TWN + j * 16 + lrow;
            atomicAdd(&wmean[b * 512 + col], (64.0f * ALPHA * ALPHA) * v);
        }
    }
}

// ---------------------------------------------------------------------------
// tail1: blocks 0..255 zret (XCD-pinned by b); block 256 dkl_w.
// ---------------------------------------------------------------------------
__global__ __launch_bounds__(256)
void tail1_kernel(const unsigned short* __restrict__ wTb,
                  const unsigned short* __restrict__ ztb,
                  const float* __restrict__ wmean, const float* __restrict__ wlv,
                  float* __restrict__ out)
{
    __shared__ __align__(16) float smemf[1024];
    const int blk = blockIdx.x, tid = threadIdx.x;
    if (blk < 256) {
        float* wms = smemf;                  // 512
        float* ys  = smemf + 512;            // 256
        float* red2 = smemf + 768;           // 256
        const int r8 = blk & 7, t8 = blk >> 3;
        const int b = r8 + 8 * (t8 & 1), ct = t8 >> 1;   // b XCD-pinned
        wms[tid] = wmean[b * 512 + tid];
        wms[tid + 256] = wmean[b * 512 + 256 + tid];
        __syncthreads();
        {
            const unsigned short* wp = wTb + (long long)b * 131072 + tid;
            float yv = 0.f;
#pragma unroll 8
            for (int k = 0; k < 512; ++k)
                yv = fmaf(wms[k], bf2f(wp[(long long)k * 256]), yv);
            ys[tid] = yv;
        }
        __syncthreads();
        const int c = ct * 128 + (tid & 127), sh = tid >> 7;
        const unsigned short* zp = ztb + (long long)b * 524288 + c;
        float acc2 = 0.f;
        const int sbase = sh * 128;
#pragma unroll 8
        for (int s = 0; s < 128; ++s)
            acc2 = fmaf(ys[sbase + s], bf2f(zp[(long long)(sbase + s) * 2048]), acc2);
        red2[tid] = acc2; __syncthreads();
        if (sh == 0)
            out[(long long)b * 2048 + c] = (8.0f * ALPHA) * (red2[tid] + red2[tid + 128]);
    } else {
        float* red = smemf;
        float s = 0.f;
        for (int i = tid; i < 16 * 512; i += 256) { const float v = wmean[i]; s += v * v; }
        red[tid] = s; __syncthreads();
        for (int st = 128; st > 0; st >>= 1) { if (tid < st) red[tid] += red[tid + st]; __syncthreads(); }
        if (tid == 0) {
            const float l = wlv[0];
            out[327681] = 0.5f * (red[0] + 8192.0f * (expf(l) - 1.0f - l));
        }
    }
}

// ---------------------------------------------------------------------------
// tail2: interleaved co-launch of nmm+dkl (1024 blocks, compute) and zrkv
// (2304 blocks, HBM NT stream, atomicAdd into pre-zeroed out). 26 = 8 + 18.
// ---------------------------------------------------------------------------
__global__ __launch_bounds__(256)
void tail2_kernel(const unsigned short* __restrict__ wTb,
                  const unsigned short* __restrict__ ztb,
                  const float* __restrict__ mm, const float* __restrict__ mlv,
                  const float* __restrict__ WM, float* __restrict__ out)
{
    __shared__ __align__(16) unsigned char smem[34304];
    const int g = blockIdx.x, tid = threadIdx.x;
    const int grp = g / 26, p = g % 26;
    if (p < 8) {
        constexpr int BM = 128, BN = 128, TWM = 64, TWN = 64, FM = 4, FN = 4;
        unsigned short* As = (unsigned short*)smem;
        unsigned short* Bs = As + BM * 64;
        float* ivars = (float*)(smem + 32768);
        float* red = (float*)(smem + 33280);
        const int bz = ((2 * grp + p) & 7) + 8 * (grp & 1);
        const int rest = grp >> 1;
        const int by = rest & 3, bx = rest >> 2;
        const int lane = tid & 63, w = tid >> 6;
        const int wm = w >> 1, wn = w & 1;
        const int lrow = lane & 15, lk = lane >> 4;
        const int m0 = by * BM, n0 = bx * BN;

        if (tid < 128) ivars[tid] = 1.0f / (expf(mlv[m0 + tid]) + 1e-6f);

        f32x4 acc[FM][FN];
#pragma unroll
        for (int i = 0; i < FM; ++i)
#pragma unroll
            for (int j = 0; j < FN; ++j) acc[i][j] = (f32x4){0.f, 0.f, 0.f, 0.f};

        for (int k0 = 0; k0 < 256; k0 += 64) {
            stage_kcontig_b<BM>(wTb + (long long)bz * 131072 + (long long)m0 * 256 + k0, 256, As, tid);
            stage_kstrided_b<BN>(ztb + (long long)bz * 524288 + (long long)k0 * 2048 + n0, 2048, Bs, tid);
            __syncthreads();
#pragma unroll
            for (int kk = 0; kk < 2; ++kk) {
                s16x8 ah[FM], bh[FN];
#pragma unroll
                for (int i = 0; i < FM; ++i) {
                    const int row = wm * TWM + i * 16 + lrow;
                    const int s = kk * 4 + lk;
                    ah[i] = *(const s16x8*)(As + row * 64 + ((s ^ (row & 7)) << 3));
                }
#pragma unroll
                for (int j = 0; j < FN; ++j) {
                    const int col = wn * TWN + j * 16 + lrow;
                    const int s = kk * 4 + lk;
                    bh[j] = *(const s16x8*)(Bs + col * 64 + ((s ^ (col & 7)) << 3));
                }
#pragma unroll
                for (int i = 0; i < FM; ++i)
#pragma unroll
                    for (int j = 0; j < FN; ++j)
                        acc[i][j] = mfma16(ah[i], bh[j], acc[i][j]);
            }
            __syncthreads();
        }

        const float A8 = 8.0f * ALPHA;
        float da = 0.f;
#pragma unroll
        for (int i = 0; i < FM; ++i)
#pragma unroll
            for (int j = 0; j < FN; ++j) {
                const int cl = wn * TWN + j * 16 + lrow;
#pragma unroll
                for (int rr = 0; rr < 4; ++rr) {
                    const int rl = wm * TWM + i * 16 + lk * 4 + rr;
                    const float v = A8 * acc[i][j][rr];
                    const float d = v - mm[(long long)(m0 + rl) * 2048 + (n0 + cl)];
                    da = fmaf(d * d, ivars[rl], da);
                }
            }
        red[tid] = da; __syncthreads();
        for (int st = 128; st > 0; st >>= 1) { if (tid < st) red[tid] += red[tid + st]; __syncthreads(); }
        if (tid == 0) atomicAdd(&out[327680], red[0] * (1.0f / 16.0f));
    } else {
        const int z = grp * 18 + (p - 8);        // 0..2303
        const int bx = z % 288, ky = z / 288;
        const int lane = tid & 63, w = tid >> 6;
        const int d0 = bx * 64 + w * 16;
        const int kc0 = ky * 256;
        const int rr = lane & 15, kq = lane >> 4;
        const float* zr = out;                   // out[0..32768) = z_retrieved
        s16x8 areg[8];
        const float* zb = zr + rr * 2048 + kc0 + kq * 8;
#pragma unroll
        for (int s = 0; s < 8; ++s) {
            const f32x4 a0 = *(const f32x4*)(zb + s * 32);
            const f32x4 a1 = *(const f32x4*)(zb + s * 32 + 4);
            u16x8 h;
#pragma unroll
            for (int j = 0; j < 4; ++j) { h[j] = f2bf(a0[j]); h[j + 4] = f2bf(a1[j]); }
            areg[s] = __builtin_bit_cast(s16x8, h);
        }
        f32x4 acc = {0.f, 0.f, 0.f, 0.f};
        const float* wb = WM + (long long)(d0 + rr) * 2048 + kc0 + kq * 8;
#pragma unroll
        for (int s = 0; s < 8; ++s) {
            const f32x4 b0 = __builtin_nontemporal_load((const f32x4*)(wb + s * 32));
            const f32x4 b1 = __builtin_nontemporal_load((const f32x4*)(wb + s * 32 + 4));
            u16x8 h;
#pragma unroll
            for (int j = 0; j < 4; ++j) { h[j] = f2bf(b0[j]); h[j + 4] = f2bf(b1[j]); }
            acc = mfma16(areg[s], __builtin_bit_cast(s16x8, h), acc);
        }
        float* oz = out + 32768;
#pragma unroll
        for (int r = 0; r < 4; ++r)
            atomicAdd(&oz[(long long)(kq * 4 + r) * 18432 + d0 + rr], acc[r]);
    }
}

extern "C" void kernel_launch(void* const* d_in, const int* in_sizes, int n_in,
                              void* d_out, int out_size, void* d_ws, size_t ws_size,
                              hipStream_t stream)
{
    (void)in_sizes; (void)n_in; (void)out_size; (void)ws_size;
    const float* z_seq   = (const float*)d_in[0];
    const float* z_query = (const float*)d_in[1];
    const float* noise   = (const float*)d_in[2];
    const float* mm      = (const float*)d_in[3];
    const float* mlv     = (const float*)d_in[4];
    const float* wlv     = (const float*)d_in[5];
    const float* WM      = (const float*)d_in[6];
    float* out = (float*)d_out;   // [zr 32768 | Zrkv 294912 | dkl_M | dkl_w]

    char* wsb = (char*)d_ws;
    unsigned short* ztb  = (unsigned short*)(wsb);                  // 16 MB (B,S,C) bf16
    unsigned short* wTb  = (unsigned short*)(wsb + (16LL << 20));   // 4 MB (B,K,S) bf16
    float*          Gp   = (float*)(wsb + (24LL << 20));            // 8 MB: 8x (K,K) partials
    unsigned short* G1b  = (unsigned short*)(wsb + (32LL << 20));   // 0.5 MB (K,K) bf16
    unsigned short* P1b  = (unsigned short*)(wsb + (33LL << 20));   // 2 MB (C,K) bf16
    float*          qvec = (float*)(wsb + (36LL << 20));            // 16 KB
    float*          wmean = (float*)(wsb + (37LL << 20));           // 32 KB

    // 1. prep (zt + q) || G1 K-split partials (interleaved every 9th block)
    fused_prep_kernel<<<4608, 256, 0, stream>>>(z_seq, noise, z_query, mm,
                                                ztb, qvec, Gp);
    // 2. G1b = bf16(sum Gp) (coalesced) || zero wmean/Zrkv/dkl_M
    g1_reduce_zero_kernel<<<265, 256, 0, stream>>>(Gp, G1b, wmean, out);
    // 3. P1 = 8a*mm^T - 28a^2*(mm^T @ G1) -> bf16
    p1_kernel<<<256, 256, 0, stream>>>(mm, G1b, P1b);
    // 4. wT = (zt @ P1)^T bf16, + fused u -> wmean (atomics); 64x64, 2 blocks/CU
    wT_u_kernel<<<512, 256, 0, stream>>>(ztb, P1b, wTb, qvec, wmean);
    // 5. zret + dkl_w (needs wmean)
    tail1_kernel<<<257, 256, 0, stream>>>(wTb, ztb, wmean, wlv, out);
    // 6. co-launched nmm+dkl_M (compute) || zrkv stream (HBM), interleaved 8:18
    tail2_kernel<<<3328, 256, 0, stream>>>(wTb, ztb, mm, mlv, WM, out);
}

// Round 14
// 159.868 us; speedup vs baseline: 1.5954x; 1.0261x over previous
//
#include <hip/hip_runtime.h>

#define ALPHA 5.0e-4f

typedef short s16x8 __attribute__((ext_vector_type(8)));
typedef unsigned short u16x8 __attribute__((ext_vector_type(8)));
typedef unsigned short u16x4 __attribute__((ext_vector_type(4)));
typedef float f32x4 __attribute__((ext_vector_type(4)));

__device__ __forceinline__ unsigned short f2bf(float f) {
    unsigned int u = __builtin_bit_cast(unsigned int, f);
    u += 0x7fffu + ((u >> 16) & 1u);
    return (unsigned short)(u >> 16);
}
__device__ __forceinline__ float bf2f(unsigned short h) {
    return __builtin_bit_cast(float, (unsigned int)h << 16);
}
__device__ __forceinline__ f32x4 mfma16(s16x8 a, s16x8 b, f32x4 c) {
    return __builtin_amdgcn_mfma_f32_16x16x32_bf16(a, b, c, 0, 0, 0);
}

// Prefetch one 49152-float chunk of W into L2/L3 (regular loads, kept live).
__device__ __forceinline__ void prefetch_chunk(const float* __restrict__ WM,
                                               int chunk, int tid)
{
    const float4* wp = (const float4*)WM + (long long)chunk * 12288;
    float4 s = {0.f, 0.f, 0.f, 0.f};
#pragma unroll 8
    for (int i = 0; i < 48; ++i) {
        const float4 v = wp[tid + i * 256];
        s.x += v.x; s.y += v.y; s.z += v.z; s.w += v.w;
    }
    asm volatile("" :: "v"(s.x), "v"(s.y), "v"(s.z), "v"(s.w));
}

// ---------------------------------------------------------------------------
// Staging helpers -> LDS tile [ROWS][64 bf16], XOR-swizzled (slot ^= row&7).
// ---------------------------------------------------------------------------
template<int ROWS>
__device__ __forceinline__ void stage_kcontig(const float* __restrict__ src, int ld,
                                              unsigned short* __restrict__ lds, int tid)
{
#pragma unroll
    for (int it = 0; it < ROWS * 8 / 256; ++it) {
        const int g = tid + it * 256;
        const int row = g >> 3, s = g & 7;
        const float* p = src + (long long)row * ld + s * 8;
        const float4 x0 = *(const float4*)p;
        const float4 x1 = *(const float4*)(p + 4);
        u16x8 h;
        h[0] = f2bf(x0.x); h[1] = f2bf(x0.y); h[2] = f2bf(x0.z); h[3] = f2bf(x0.w);
        h[4] = f2bf(x1.x); h[5] = f2bf(x1.y); h[6] = f2bf(x1.z); h[7] = f2bf(x1.w);
        *(u16x8*)(lds + row * 64 + ((s ^ (row & 7)) << 3)) = h;
    }
}

template<int ROWS>
__device__ __forceinline__ void stage_kstrided(const float* __restrict__ src, int ld,
                                               unsigned short* __restrict__ lds, int tid)
{
    constexpr int KPT = ROWS * 64 / 256;
    const int m = tid % ROWS, kb = (tid / ROWS) * KPT;
#pragma unroll
    for (int j8 = 0; j8 < KPT / 8; ++j8) {
        u16x8 h;
#pragma unroll
        for (int j = 0; j < 8; ++j)
            h[j] = f2bf(src[(long long)(kb + j8 * 8 + j) * ld + m]);
        const int s = (kb >> 3) + j8;
        *(u16x8*)(lds + m * 64 + ((s ^ (m & 7)) << 3)) = h;
    }
}

template<int ROWS>
__device__ __forceinline__ void stage_kcontig_b(const unsigned short* __restrict__ src, int ld,
                                                unsigned short* __restrict__ lds, int tid)
{
#pragma unroll
    for (int it = 0; it < ROWS * 8 / 256; ++it) {
        const int g = tid + it * 256;
        const int row = g >> 3, s = g & 7;
        const u16x8 h = *(const u16x8*)(src + (long long)row * ld + s * 8);
        *(u16x8*)(lds + row * 64 + ((s ^ (row & 7)) << 3)) = h;
    }
}

template<int ROWS>
__device__ __forceinline__ void stage_kstrided_b(const unsigned short* __restrict__ src, int ld,
                                                 unsigned short* __restrict__ lds, int tid)
{
    constexpr int KPT = ROWS * 64 / 256;
    const int m = tid % ROWS, kb = (tid / ROWS) * KPT;
#pragma unroll
    for (int j8 = 0; j8 < KPT / 8; ++j8) {
        u16x8 h;
#pragma unroll
        for (int j = 0; j < 8; ++j)
            h[j] = src[(long long)(kb + j8 * 8 + j) * ld + m];
        const int s = (kb >> 3) + j8;
        *(u16x8*)(lds + m * 64 + ((s ^ (m & 7)) << 3)) = h;
    }
}

// ---------------------------------------------------------------------------
// GEMM device body (f32 inputs, f32 store):  D = op(A)@op(B)
// ---------------------------------------------------------------------------
template<int BM, int BN, bool TA, bool TB>
__device__ __forceinline__
void gemm_dev_f32(int bx, int by,
                  const float* __restrict__ A, int lda,
                  const float* __restrict__ B, int ldb,
                  float* __restrict__ D, int ldd, int Kd)
{
    constexpr int TWM = BM / 2, TWN = BN / 2;
    constexpr int FM = TWM / 16, FN = TWN / 16;
    __shared__ unsigned short As[BM * 64];
    __shared__ unsigned short Bs[BN * 64];

    const int tid = threadIdx.x;
    const int lane = tid & 63, w = tid >> 6;
    const int wm = w >> 1, wn = w & 1;
    const int lrow = lane & 15, lk = lane >> 4;
    const int m0 = by * BM, n0 = bx * BN;

    f32x4 acc[FM][FN];
#pragma unroll
    for (int i = 0; i < FM; ++i)
#pragma unroll
        for (int j = 0; j < FN; ++j) acc[i][j] = (f32x4){0.f, 0.f, 0.f, 0.f};

    for (int k0 = 0; k0 < Kd; k0 += 64) {
        if (!TA) stage_kcontig<BM>(A + (long long)m0 * lda + k0, lda, As, tid);
        else     stage_kstrided<BM>(A + (long long)k0 * lda + m0, lda, As, tid);
        if (TB)  stage_kcontig<BN>(B + (long long)n0 * ldb + k0, ldb, Bs, tid);
        else     stage_kstrided<BN>(B + (long long)k0 * ldb + n0, ldb, Bs, tid);
        __syncthreads();
#pragma unroll
        for (int kk = 0; kk < 2; ++kk) {
            s16x8 ah[FM], bh[FN];
#pragma unroll
            for (int i = 0; i < FM; ++i) {
                const int row = wm * TWM + i * 16 + lrow;
                const int s = kk * 4 + lk;
                ah[i] = *(const s16x8*)(As + row * 64 + ((s ^ (row & 7)) << 3));
            }
#pragma unroll
            for (int j = 0; j < FN; ++j) {
                const int col = wn * TWN + j * 16 + lrow;
                const int s = kk * 4 + lk;
                bh[j] = *(const s16x8*)(Bs + col * 64 + ((s ^ (col & 7)) << 3));
            }
#pragma unroll
            for (int i = 0; i < FM; ++i)
#pragma unroll
                for (int j = 0; j < FN; ++j)
                    acc[i][j] = mfma16(ah[i], bh[j], acc[i][j]);
        }
        __syncthreads();
    }

#pragma unroll
    for (int i = 0; i < FM; ++i)
#pragma unroll
        for (int j = 0; j < FN; ++j) {
            const int col = n0 + wn * TWN + j * 16 + lrow;
#pragma unroll
            for (int r = 0; r < 4; ++r) {
                const int row = m0 + wm * TWM + i * 16 + lk * 4 + r;
                D[(long long)row * ldd + col] = acc[i][j][r];
            }
        }
}

// ---------------------------------------------------------------------------
// fused_prep: blk%9==8 -> G1 partial GEMM (Gp[ky] = mm_ky @ mm_ky^T); else zt/q.
// ---------------------------------------------------------------------------
__global__ __launch_bounds__(256)
void fused_prep_kernel(const float* __restrict__ zs, const float* __restrict__ no,
                       const float* __restrict__ zq, const float* __restrict__ mm,
                       unsigned short* __restrict__ ztb, float* __restrict__ q,
                       float* __restrict__ Gp)
{
    const int blk = blockIdx.x, t = threadIdx.x;
    if (blk % 9 == 8) {
        const int g = blk / 9;              // 0..511
        const int ky = g & 7;               // K-chunk
        const int tile = g >> 3;            // 0..63
        gemm_dev_f32<64, 64, false, true>(
            tile & 7, tile >> 3,
            mm + ky * 256, 2048, mm + ky * 256, 2048,
            Gp + (long long)ky * 262144, 512, 256);
    } else {
        const int bs = blk - blk / 9;       // 0..4095 = b*256 + s
        const int b = bs >> 8, sI = bs & 255;
        const long long in = ((long long)sI * 16 + b) * 2048 + t * 8;
        const f32x4 z0 = __builtin_nontemporal_load((const f32x4*)(zs + in));
        const f32x4 z1 = __builtin_nontemporal_load((const f32x4*)(zs + in + 4));
        const f32x4 n0 = __builtin_nontemporal_load((const f32x4*)(no + in));
        const f32x4 n1 = __builtin_nontemporal_load((const f32x4*)(no + in + 4));
        float zf[8];
#pragma unroll
        for (int j = 0; j < 4; ++j) {
            zf[j]     = fmaf(0.01f, n0[j], z0[j]);
            zf[j + 4] = fmaf(0.01f, n1[j], z1[j]);
        }
        u16x8 o;
#pragma unroll
        for (int j = 0; j < 8; ++j) o[j] = f2bf(zf[j]);
        *(u16x8*)(ztb + ((long long)bs * 2048 + t * 8)) = o;
        const float4 q0 = *(const float4*)(zq + b * 2048 + t * 8);
        const float4 q1 = *(const float4*)(zq + b * 2048 + t * 8 + 4);
        float qa = zf[0] * q0.x + zf[1] * q0.y + zf[2] * q0.z + zf[3] * q0.w
                 + zf[4] * q1.x + zf[5] * q1.y + zf[6] * q1.z + zf[7] * q1.w;
        __shared__ float red[256];
        red[t] = qa; __syncthreads();
        for (int st = 128; st > 0; st >>= 1) { if (t < st) red[t] += red[t + st]; __syncthreads(); }
        if (t == 0) q[bs] = red[0];
    }
}

// ---------------------------------------------------------------------------
// vg: blocks 0..511 V = zt @ mm^T -> bf16 (4096,512,2048), XCD-pinned A reuse;
//     512..767 G1b = bf16(sum Gp); 768..776 zero wmean/Zrkv/dkl_M;
//     777..1288 prefetch W chunks 0..511 (~100 MB into L3).
// ---------------------------------------------------------------------------
__global__ __launch_bounds__(256)
void vg_kernel(const unsigned short* __restrict__ ztb, const float* __restrict__ mm,
               const float* __restrict__ Gp, const float* __restrict__ WM,
               unsigned short* __restrict__ Vb, unsigned short* __restrict__ G1b,
               float* __restrict__ wmean, float* __restrict__ out)
{
    const int blk = blockIdx.x, tid = threadIdx.x;
    if (blk < 512) {
        constexpr int BM = 64, BN = 64, TWM = 32, TWN = 32, FM = 2, FN = 2;
        __shared__ unsigned short As[BM * 64];
        __shared__ unsigned short Bs[BN * 64];
        const int r = blk & 7, t = blk >> 3;
        const int by = r + 8 * (t & 7), bx = t >> 3;   // by 0..63, bx 0..7
        const int lane = tid & 63, w = tid >> 6;
        const int wm = w >> 1, wn = w & 1;
        const int lrow = lane & 15, lk = lane >> 4;
        const int m0 = by * BM, n0 = bx * BN;

        f32x4 acc[FM][FN];
#pragma unroll
        for (int i = 0; i < FM; ++i)
#pragma unroll
            for (int j = 0; j < FN; ++j) acc[i][j] = (f32x4){0.f, 0.f, 0.f, 0.f};

        for (int k0 = 0; k0 < 2048; k0 += 64) {
            stage_kcontig_b<BM>(ztb + (long long)m0 * 2048 + k0, 2048, As, tid);
            stage_kcontig<BN>(mm + (long long)n0 * 2048 + k0, 2048, Bs, tid);
            __syncthreads();
#pragma unroll
            for (int kk = 0; kk < 2; ++kk) {
                s16x8 ah[FM], bh[FN];
#pragma unroll
                for (int i = 0; i < FM; ++i) {
                    const int row = wm * TWM + i * 16 + lrow;
                    const int s = kk * 4 + lk;
                    ah[i] = *(const s16x8*)(As + row * 64 + ((s ^ (row & 7)) << 3));
                }
#pragma unroll
                for (int j = 0; j < FN; ++j) {
                    const int col = wn * TWN + j * 16 + lrow;
                    const int s = kk * 4 + lk;
                    bh[j] = *(const s16x8*)(Bs + col * 64 + ((s ^ (col & 7)) << 3));
                }
#pragma unroll
                for (int i = 0; i < FM; ++i)
#pragma unroll
                    for (int j = 0; j < FN; ++j)
                        acc[i][j] = mfma16(ah[i], bh[j], acc[i][j]);
            }
            __syncthreads();
        }

#pragma unroll
        for (int i = 0; i < FM; ++i)
#pragma unroll
            for (int j = 0; j < FN; ++j) {
                const int col = n0 + wn * TWN + j * 16 + lrow;
#pragma unroll
                for (int rr = 0; rr < 4; ++rr) {
                    const int row = m0 + wm * TWM + i * 16 + lk * 4 + rr;
                    Vb[(long long)row * 512 + col] = f2bf(acc[i][j][rr]);
                }
            }
    } else if (blk < 768) {
        const int idx = (blk - 512) * 256 + tid;     // 0..65535 float4s
        f32x4 s = {0.f, 0.f, 0.f, 0.f};
#pragma unroll
        for (int p = 0; p < 8; ++p) {
            const f32x4 v = *(const f32x4*)(Gp + (long long)p * 262144 + idx * 4);
            s[0] += v[0]; s[1] += v[1]; s[2] += v[2]; s[3] += v[3];
        }
        u16x4 h;
#pragma unroll
        for (int j = 0; j < 4; ++j) h[j] = f2bf(s[j]);
        *(u16x4*)(G1b + idx * 4) = h;
    } else if (blk < 777) {
        const int zb = blk - 768;            // 0..8
        float4* oz = (float4*)(out + 32768);
        const int base = (zb * 256 + tid) * 32;
#pragma unroll
        for (int i = 0; i < 32; ++i) oz[base + i] = (float4){0.f, 0.f, 0.f, 0.f};
        if (zb == 0) {
            float4* wm4 = (float4*)wmean;
            for (int i = tid; i < 2048; i += 256) wm4[i] = (float4){0.f, 0.f, 0.f, 0.f};
            if (tid == 0) out[327680] = 0.f;
        }
    } else {
        prefetch_chunk(WM, blk - 777, tid);  // chunks 0..511
    }
}

// ---------------------------------------------------------------------------
// wT2: w = 8a*V - 28a^2*(V @ G1)  (K=512, G1 symmetric -> row-contig staging),
// store wTb transposed bf16 + fused u -> wmean (atomics). 512 blocks.
// ---------------------------------------------------------------------------
__global__ __launch_bounds__(256)
void wT2_kernel(const unsigned short* __restrict__ Vb,
                const unsigned short* __restrict__ G1b,
                unsigned short* __restrict__ wTb,
                const float* __restrict__ q, float* __restrict__ wmean)
{
    constexpr int BM = 64, BN = 64, TWM = 32, TWN = 32, FM = 2, FN = 2;
    __shared__ unsigned short As[BM * 64];
    __shared__ unsigned short Bs[BN * 64];
    const int lin = blockIdx.x;
    const int r = lin & 7, t = lin >> 3;
    const int by = r + 8 * (t & 7), bx = t >> 3;  // by 0..63, bx 0..7
    const int tid = threadIdx.x;
    const int lane = tid & 63, w = tid >> 6;
    const int wm = w >> 1, wn = w & 1;
    const int lrow = lane & 15, lk = lane >> 4;
    const int m0 = by * BM, n0 = bx * BN;

    f32x4 acc[FM][FN];
#pragma unroll
    for (int i = 0; i < FM; ++i)
#pragma unroll
        for (int j = 0; j < FN; ++j) acc[i][j] = (f32x4){0.f, 0.f, 0.f, 0.f};

    for (int k0 = 0; k0 < 512; k0 += 64) {
        stage_kcontig_b<BM>(Vb + (long long)m0 * 512 + k0, 512, As, tid);
        stage_kcontig_b<BN>(G1b + (long long)n0 * 512 + k0, 512, Bs, tid);  // symmetric
        __syncthreads();
#pragma unroll
        for (int kk = 0; kk < 2; ++kk) {
            s16x8 ah[FM], bh[FN];
#pragma unroll
            for (int i = 0; i < FM; ++i) {
                const int row = wm * TWM + i * 16 + lrow;
                const int s = kk * 4 + lk;
                ah[i] = *(const s16x8*)(As + row * 64 + ((s ^ (row & 7)) << 3));
            }
#pragma unroll
            for (int j = 0; j < FN; ++j) {
                const int col = wn * TWN + j * 16 + lrow;
                const int s = kk * 4 + lk;
                bh[j] = *(const s16x8*)(Bs + col * 64 + ((s ^ (col & 7)) << 3));
            }
#pragma unroll
            for (int i = 0; i < FM; ++i)
#pragma unroll
                for (int j = 0; j < FN; ++j)
                    acc[i][j] = mfma16(ah[i], bh[j], acc[i][j]);
        }
        __syncthreads();
    }

    const float a8 = 8.0f * ALPHA, a28 = -28.0f * ALPHA * ALPHA;
    float up[FN] = {0.f, 0.f};
#pragma unroll
    for (int i = 0; i < FM; ++i)
#pragma unroll
        for (int rr = 0; rr < 4; ++rr) {
            const int row = m0 + wm * TWM + i * 16 + lk * 4 + rr;
            const float qv = q[row];
#pragma unroll
            for (int j = 0; j < FN; ++j) {
                const int col = n0 + wn * TWN + j * 16 + lrow;
                const float v = fmaf(a8, bf2f(Vb[(long long)row * 512 + col]),
                                     a28 * acc[i][j][rr]);
                wTb[(long long)(row >> 8) * 131072 + (long long)col * 256 + (row & 255)] = f2bf(v);
                up[j] = fmaf(v, qv, up[j]);
            }
        }
    const int b = m0 >> 8;
#pragma unroll
    for (int j = 0; j < FN; ++j) {
        float v = up[j];
        v += __shfl_xor(v, 16);
        v += __shfl_xor(v, 32);
        if (lk == 0) {
            const int col = n0 + wn * TWN + j * 16 + lrow;
            atomicAdd(&wmean[b * 512 + col], (64.0f * ALPHA * ALPHA) * v);
        }
    }
}

// ---------------------------------------------------------------------------
// tail1: blocks 0..255 zret (XCD-pinned by b); 256 dkl_w;
//        257..512 prefetch W chunks 512..767 (~50 MB into L3).
// ---------------------------------------------------------------------------
__global__ __launch_bounds__(256)
void tail1_kernel(const unsigned short* __restrict__ wTb,
                  const unsigned short* __restrict__ ztb,
                  const float* __restrict__ wmean, const float* __restrict__ wlv,
                  const float* __restrict__ WM, float* __restrict__ out)
{
    __shared__ __align__(16) float smemf[1024];
    const int blk = blockIdx.x, tid = threadIdx.x;
    if (blk < 256) {
        float* wms = smemf;
        float* ys  = smemf + 512;
        float* red2 = smemf + 768;
        const int r8 = blk & 7, t8 = blk >> 3;
        const int b = r8 + 8 * (t8 & 1), ct = t8 >> 1;
        wms[tid] = wmean[b * 512 + tid];
        wms[tid + 256] = wmean[b * 512 + 256 + tid];
        __syncthreads();
        {
            const unsigned short* wp = wTb + (long long)b * 131072 + tid;
            float yv = 0.f;
#pragma unroll 8
            for (int k = 0; k < 512; ++k)
                yv = fmaf(wms[k], bf2f(wp[(long long)k * 256]), yv);
            ys[tid] = yv;
        }
        __syncthreads();
        const int c = ct * 128 + (tid & 127), sh = tid >> 7;
        const unsigned short* zp = ztb + (long long)b * 524288 + c;
        float acc2 = 0.f;
        const int sbase = sh * 128;
#pragma unroll 8
        for (int s = 0; s < 128; ++s)
            acc2 = fmaf(ys[sbase + s], bf2f(zp[(long long)(sbase + s) * 2048]), acc2);
        red2[tid] = acc2; __syncthreads();
        if (sh == 0)
            out[(long long)b * 2048 + c] = (8.0f * ALPHA) * (red2[tid] + red2[tid + 128]);
    } else if (blk == 256) {
        float* red = smemf;
        float s = 0.f;
        for (int i = tid; i < 16 * 512; i += 256) { const float v = wmean[i]; s += v * v; }
        red[tid] = s; __syncthreads();
        for (int st = 128; st > 0; st >>= 1) { if (tid < st) red[tid] += red[tid + st]; __syncthreads(); }
        if (tid == 0) {
            const float l = wlv[0];
            out[327681] = 0.5f * (red[0] + 8192.0f * (expf(l) - 1.0f - l));
        }
    } else {
        prefetch_chunk(WM, 512 + (blk - 257), tid);   // chunks 512..767
    }
}

// ---------------------------------------------------------------------------
// tail2: interleaved co-launch of nmm+dkl (1024 blocks) and zrkv (2304 blocks,
// W now L3-resident -> regular loads, atomicAdd into pre-zeroed out). 26=8+18.
// ---------------------------------------------------------------------------
__global__ __launch_bounds__(256)
void tail2_kernel(const unsigned short* __restrict__ wTb,
                  const unsigned short* __restrict__ ztb,
                  const float* __restrict__ mm, const float* __restrict__ mlv,
                  const float* __restrict__ WM, float* __restrict__ out)
{
    __shared__ __align__(16) unsigned char smem[34304];
    const int g = blockIdx.x, tid = threadIdx.x;
    const int grp = g / 26, p = g % 26;
    if (p < 8) {
        constexpr int BM = 128, BN = 128, TWM = 64, TWN = 64, FM = 4, FN = 4;
        unsigned short* As = (unsigned short*)smem;
        unsigned short* Bs = As + BM * 64;
        float* ivars = (float*)(smem + 32768);
        float* red = (float*)(smem + 33280);
        const int bz = ((2 * grp + p) & 7) + 8 * (grp & 1);
        const int rest = grp >> 1;
        const int by = rest & 3, bx = rest >> 2;
        const int lane = tid & 63, w = tid >> 6;
        const int wm = w >> 1, wn = w & 1;
        const int lrow = lane & 15, lk = lane >> 4;
        const int m0 = by * BM, n0 = bx * BN;

        if (tid < 128) ivars[tid] = 1.0f / (expf(mlv[m0 + tid]) + 1e-6f);

        f32x4 acc[FM][FN];
#pragma unroll
        for (int i = 0; i < FM; ++i)
#pragma unroll
            for (int j = 0; j < FN; ++j) acc[i][j] = (f32x4){0.f, 0.f, 0.f, 0.f};

        for (int k0 = 0; k0 < 256; k0 += 64) {
            stage_kcontig_b<BM>(wTb + (long long)bz * 131072 + (long long)m0 * 256 + k0, 256, As, tid);
            stage_kstrided_b<BN>(ztb + (long long)bz * 524288 + (long long)k0 * 2048 + n0, 2048, Bs, tid);
            __syncthreads();
#pragma unroll
            for (int kk = 0; kk < 2; ++kk) {
                s16x8 ah[FM], bh[FN];
#pragma unroll
                for (int i = 0; i < FM; ++i) {
                    const int row = wm * TWM + i * 16 + lrow;
                    const int s = kk * 4 + lk;
                    ah[i] = *(const s16x8*)(As + row * 64 + ((s ^ (row & 7)) << 3));
                }
#pragma unroll
                for (int j = 0; j < FN; ++j) {
                    const int col = wn * TWN + j * 16 + lrow;
                    const int s = kk * 4 + lk;
                    bh[j] = *(const s16x8*)(Bs + col * 64 + ((s ^ (col & 7)) << 3));
                }
#pragma unroll
                for (int i = 0; i < FM; ++i)
#pragma unroll
                    for (int j = 0; j < FN; ++j)
                        acc[i][j] = mfma16(ah[i], bh[j], acc[i][j]);
            }
            __syncthreads();
        }

        const float A8 = 8.0f * ALPHA;
        float da = 0.f;
#pragma unroll
        for (int i = 0; i < FM; ++i)
#pragma unroll
            for (int j = 0; j < FN; ++j) {
                const int cl = wn * TWN + j * 16 + lrow;
#pragma unroll
                for (int rr = 0; rr < 4; ++rr) {
                    const int rl = wm * TWM + i * 16 + lk * 4 + rr;
                    const float v = A8 * acc[i][j][rr];
                    const float d = v - mm[(long long)(m0 + rl) * 2048 + (n0 + cl)];
                    da = fmaf(d * d, ivars[rl], da);
                }
            }
        red[tid] = da; __syncthreads();
        for (int st = 128; st > 0; st >>= 1) { if (tid < st) red[tid] += red[tid + st]; __syncthreads(); }
        if (tid == 0) atomicAdd(&out[327680], red[0] * (1.0f / 16.0f));
    } else {
        const int z = grp * 18 + (p - 8);        // 0..2303
        const int bx = z % 288, ky = z / 288;
        const int lane = tid & 63, w = tid >> 6;
        const int d0 = bx * 64 + w * 16;
        const int kc0 = ky * 256;
        const int rr = lane & 15, kq = lane >> 4;
        const float* zr = out;                   // out[0..32768) = z_retrieved
        s16x8 areg[8];
        const float* zb = zr + rr * 2048 + kc0 + kq * 8;
#pragma unroll
        for (int s = 0; s < 8; ++s) {
            const f32x4 a0 = *(const f32x4*)(zb + s * 32);
            const f32x4 a1 = *(const f32x4*)(zb + s * 32 + 4);
            u16x8 h;
#pragma unroll
            for (int j = 0; j < 4; ++j) { h[j] = f2bf(a0[j]); h[j + 4] = f2bf(a1[j]); }
            areg[s] = __builtin_bit_cast(s16x8, h);
        }
        f32x4 acc = {0.f, 0.f, 0.f, 0.f};
        const float* wb = WM + (long long)(d0 + rr) * 2048 + kc0 + kq * 8;
#pragma unroll
        for (int s = 0; s < 8; ++s) {
            const f32x4 b0 = *(const f32x4*)(wb + s * 32);
            const f32x4 b1 = *(const f32x4*)(wb + s * 32 + 4);
            u16x8 h;
#pragma unroll
            for (int j = 0; j < 4; ++j) { h[j] = f2bf(b0[j]); h[j + 4] = f2bf(b1[j]); }
            acc = mfma16(areg[s], __builtin_bit_cast(s16x8, h), acc);
        }
        float* oz = out + 32768;
#pragma unroll
        for (int r = 0; r < 4; ++r)
            atomicAdd(&oz[(long long)(kq * 4 + r) * 18432 + d0 + rr], acc[r]);
    }
}

extern "C" void kernel_launch(void* const* d_in, const int* in_sizes, int n_in,
                              void* d_out, int out_size, void* d_ws, size_t ws_size,
                              hipStream_t stream)
{
    (void)in_sizes; (void)n_in; (void)out_size; (void)ws_size;
    const float* z_seq   = (const float*)d_in[0];
    const float* z_query = (const float*)d_in[1];
    const float* noise   = (const float*)d_in[2];
    const float* mm      = (const float*)d_in[3];
    const float* mlv     = (const float*)d_in[4];
    const float* wlv     = (const float*)d_in[5];
    const float* WM      = (const float*)d_in[6];
    float* out = (float*)d_out;   // [zr 32768 | Zrkv 294912 | dkl_M | dkl_w]

    char* wsb = (char*)d_ws;
    unsigned short* ztb  = (unsigned short*)(wsb);                  // 16 MB (B,S,C) bf16
    unsigned short* wTb  = (unsigned short*)(wsb + (16LL << 20));   // 4 MB (B,K,S) bf16
    float*          Gp   = (float*)(wsb + (24LL << 20));            // 8 MB: 8x (K,K) partials
    unsigned short* G1b  = (unsigned short*)(wsb + (32LL << 20));   // 0.5 MB (K,K) bf16
    unsigned short* Vb   = (unsigned short*)(wsb + (33LL << 20));   // 4 MB (B*S,K) bf16
    float*          qvec = (float*)(wsb + (38LL << 20));            // 16 KB
    float*          wmean = (float*)(wsb + (39LL << 20));           // 32 KB

    // 1. prep (zt + q) || G1 K-split partials (interleaved every 9th block)
    fused_prep_kernel<<<4608, 256, 0, stream>>>(z_seq, noise, z_query, mm,
                                                ztb, qvec, Gp);
    // 2. V = zt @ mm^T || G1b reduce || zero wmean/Zrkv/dkl_M || prefetch W[0:100MB]
    vg_kernel<<<1289, 256, 0, stream>>>(ztb, mm, Gp, WM, Vb, G1b, wmean, out);
    // 3. w = 8a*V - 28a^2*(V@G1), wT store + fused u -> wmean
    wT2_kernel<<<512, 256, 0, stream>>>(Vb, G1b, wTb, qvec, wmean);
    // 4. zret + dkl_w || prefetch W[100:151MB]
    tail1_kernel<<<513, 256, 0, stream>>>(wTb, ztb, wmean, wlv, WM, out);
    // 5. co-launched nmm+dkl_M (compute) || zrkv stream (L3-hot W), 8:18
    tail2_kernel<<<3328, 256, 0, stream>>>(wTb, ztb, mm, mlv, WM, out);
}